// Round 1
// baseline (9530.129 us; speedup 1.0000x reference)
//
#include <hip/hip_runtime.h>
#include <cstdint>

#define NB    4096
#define NNODE 64
#define FEAT  32
#define H     128
#define NE    4
#define NL    3
#define PITCH 132   // 128 + 4: keeps float4 (16B) alignment, spreads rows across banks

__device__ __forceinline__ float sigm(float v) { return 1.0f / (1.0f + __expf(-v)); }
__device__ __forceinline__ float tanh_(float v) {
  v = fminf(fmaxf(v, -15.f), 15.f);
  float e = __expf(-2.f * v);
  return (1.f - e) / (1.f + e);
}

// One 6-slice GRU partial-matmul: stage 16 rows (gate*H + c0 .. +15) of MAT into
// s_w (coalesced global read, conflict-free LDS write), then each thread
// accumulates its 4 rows x 1 column dot products. Macro (not lambda) so the
// accumulator array is guaranteed SROA'd into registers.
#define GRU_SLICE(MAT, GATE, SRC, AC)                                          \
  do {                                                                         \
    _Pragma("unroll")                                                          \
    for (int q_ = 0; q_ < 8; ++q_) {                                           \
      int idx_ = t + q_ * 256;                                                 \
      int r_ = idx_ >> 7, k_ = idx_ & 127;                                     \
      s_w[r_ * PITCH + k_] = (MAT)[((GATE) * H + c0 + r_) * H + k_];           \
    }                                                                          \
    __syncthreads();                                                           \
    _Pragma("unroll")                                                          \
    for (int jj_ = 0; jj_ < 4; ++jj_) (AC)[jj_] = 0.f;                         \
    for (int k4_ = 0; k4_ < 32; ++k4_) {                                       \
      float4 w4_ = *reinterpret_cast<const float4*>(&s_w[g16 * PITCH + k4_ * 4]); \
      _Pragma("unroll")                                                        \
      for (int jj_ = 0; jj_ < 4; ++jj_) {                                      \
        int n_ = nsub + 16 * jj_;                                              \
        float4 v4_ = *reinterpret_cast<const float4*>(&(SRC)[n_ * PITCH + k4_ * 4]); \
        (AC)[jj_] += v4_.x * w4_.x + v4_.y * w4_.y + v4_.z * w4_.z + v4_.w * w4_.w; \
      }                                                                        \
    }                                                                          \
    __syncthreads();                                                           \
  } while (0)

__global__ __launch_bounds__(256, 2) void mpnn_kernel(
    const float* __restrict__ x, const float* __restrict__ adj,
    const float* __restrict__ in_w, const float* __restrict__ in_b,
    const float* __restrict__ out_w, const float* __restrict__ out_b,
    const float* __restrict__ gc_w, const float* __restrict__ gc_b,
    const float* __restrict__ w_ih, const float* __restrict__ w_hh,
    const float* __restrict__ b_ih, const float* __restrict__ b_hh,
    float* __restrict__ out)
{
  __shared__ __align__(16) float s_cur[NNODE * PITCH];  // hidden / cur
  __shared__ __align__(16) float s_tmp[NNODE * PITCH];  // x-stage, S, agg(xf)
  __shared__ __align__(16) float s_w[16 * PITCH];       // weight slice staging

  const int t = threadIdx.x;
  const int b = blockIdx.x;
  float* __restrict__ ob = out + (size_t)b * NNODE * H;

  // ---- stage x[b] (64x32) into s_tmp ----
  {
    const float4* xb = reinterpret_cast<const float4*>(x + (size_t)b * NNODE * FEAT);
    float4* st = reinterpret_cast<float4*>(s_tmp);
    st[t] = xb[t];
    st[t + 256] = xb[t + 256];
  }
  __syncthreads();

  const int hh = t & 127, np = t >> 7;    // (column, row-parity) mapping
  const int g16 = t & 15, nsub = t >> 4;  // GRU mapping

  // ---- input embedding: cur[n][hh] = sum_d x[n,d]*in_w[n,d,hh] + in_b[n,hh]
  for (int m = 0; m < 32; ++m) {
    const int n = np + 2 * m;
    const float* w = in_w + (size_t)n * FEAT * H + hh;
    float a0 = 0, a1 = 0, a2 = 0, a3 = 0;
    #pragma unroll
    for (int d4 = 0; d4 < 8; ++d4) {
      float4 xv = *reinterpret_cast<const float4*>(&s_tmp[n * FEAT + d4 * 4]);
      a0 += xv.x * w[(d4 * 4 + 0) * H];
      a1 += xv.y * w[(d4 * 4 + 1) * H];
      a2 += xv.z * w[(d4 * 4 + 2) * H];
      a3 += xv.w * w[(d4 * 4 + 3) * H];
    }
    s_cur[n * PITCH + hh] = (a0 + a1) + (a2 + a3) + in_b[n * H + hh];
  }
  __syncthreads();

  for (int layer = 0; layer < NL; ++layer) {
    float agg[32];
    #pragma unroll
    for (int m = 0; m < 32; ++m) agg[m] = 0.f;

    // ======== relational GCN: agg = mean_e relu(adj_e @ (cur @ W_e) + b_e) ====
    for (int e = 0; e < NE; ++e) {
      const float* gw = gc_w + (size_t)(layer * NE + e) * H * H;
      // (a) S = cur @ W_e  (S lives in s_tmp), k staged in chunks of 16
      for (int kc = 0; kc < 8; ++kc) {
        #pragma unroll
        for (int q = 0; q < 8; ++q) {
          int idx = t + q * 256;
          s_w[idx] = gw[kc * 16 * H + idx];     // [16][128] packed
        }
        __syncthreads();
        for (int g = 0; g < 8; ++g) {
          float acc[4];
          #pragma unroll
          for (int rr = 0; rr < 4; ++rr) {
            int n = np + 2 * (g * 4 + rr);
            acc[rr] = (kc == 0) ? 0.f : s_tmp[n * PITCH + hh];
          }
          #pragma unroll
          for (int k4 = 0; k4 < 4; ++k4) {
            float w0 = s_w[(k4 * 4 + 0) * H + hh];
            float w1 = s_w[(k4 * 4 + 1) * H + hh];
            float w2 = s_w[(k4 * 4 + 2) * H + hh];
            float w3 = s_w[(k4 * 4 + 3) * H + hh];
            #pragma unroll
            for (int rr = 0; rr < 4; ++rr) {
              int n = np + 2 * (g * 4 + rr);
              float4 c4 = *reinterpret_cast<const float4*>(&s_cur[n * PITCH + kc * 16 + k4 * 4]);
              acc[rr] += c4.x * w0 + c4.y * w1 + c4.z * w2 + c4.w * w3;
            }
          }
          #pragma unroll
          for (int rr = 0; rr < 4; ++rr) {
            int n = np + 2 * (g * 4 + rr);
            s_tmp[n * PITCH + hh] = acc[rr];
          }
        }
        __syncthreads();
      }
      // (b) agg += relu(adj_e @ S + bias)/4   (agg in registers, row-partitioned)
      {
        const float* adj_e = adj + ((size_t)b * NE + e) * NNODE * NNODE;
        const float bias_e = gc_b[(layer * NE + e) * H + hh];
        #pragma unroll
        for (int g = 0; g < 8; ++g) {
          float o[4] = {0.f, 0.f, 0.f, 0.f};
          for (int j4 = 0; j4 < 16; ++j4) {
            float sv0 = s_tmp[(j4 * 4 + 0) * PITCH + hh];
            float sv1 = s_tmp[(j4 * 4 + 1) * PITCH + hh];
            float sv2 = s_tmp[(j4 * 4 + 2) * PITCH + hh];
            float sv3 = s_tmp[(j4 * 4 + 3) * PITCH + hh];
            #pragma unroll
            for (int rr = 0; rr < 4; ++rr) {
              int n = np + 2 * (g * 4 + rr);
              float4 av = *reinterpret_cast<const float4*>(&adj_e[n * NNODE + j4 * 4]);
              o[rr] += av.x * sv0 + av.y * sv1 + av.z * sv2 + av.w * sv3;
            }
          }
          #pragma unroll
          for (int rr = 0; rr < 4; ++rr)
            agg[g * 4 + rr] += 0.25f * fmaxf(o[rr] + bias_e, 0.f);
        }
      }
      __syncthreads();  // all S reads done before S is rewritten / repurposed
    }

    // agg -> s_tmp (xf for the GRU)
    #pragma unroll
    for (int m = 0; m < 32; ++m) s_tmp[(np + 2 * m) * PITCH + hh] = agg[m];
    __syncthreads();

    // ======== GRU cell: hidden = GRU(xf=s_tmp, h=s_cur) ========
    // h' spills through d_out[b] (each thread touches only its own cells),
    // read back after all gh-matmul reads of s_cur are complete.
    for (int c = 0; c < 8; ++c) {
      const int c0 = c * 16;
      float air[4], aiz[4], ain[4], ahr[4], ahz[4], ahn[4];
      GRU_SLICE(w_ih, 0, s_tmp, air);
      GRU_SLICE(w_ih, 1, s_tmp, aiz);
      GRU_SLICE(w_ih, 2, s_tmp, ain);
      GRU_SLICE(w_hh, 0, s_cur, ahr);
      GRU_SLICE(w_hh, 1, s_cur, ahz);
      GRU_SLICE(w_hh, 2, s_cur, ahn);
      const float bir = b_ih[c0 + g16], biz = b_ih[H + c0 + g16], bin = b_ih[2 * H + c0 + g16];
      const float bhr = b_hh[c0 + g16], bhz = b_hh[H + c0 + g16], bhn = b_hh[2 * H + c0 + g16];
      #pragma unroll
      for (int jj = 0; jj < 4; ++jj) {
        int n = nsub + 16 * jj;
        float r = sigm(air[jj] + bir + ahr[jj] + bhr);
        float z = sigm(aiz[jj] + biz + ahz[jj] + bhz);
        float nn = tanh_(ain[jj] + bin + r * (ahn[jj] + bhn));
        float hold = s_cur[n * PITCH + c0 + g16];
        ob[n * H + c0 + g16] = (1.f - z) * nn + z * hold;
      }
    }
    __syncthreads();
    #pragma unroll
    for (int c = 0; c < 8; ++c) {
      #pragma unroll
      for (int jj = 0; jj < 4; ++jj) {
        int n = nsub + 16 * jj;
        s_cur[n * PITCH + c * 16 + g16] = ob[n * H + c * 16 + g16];
      }
    }
    __syncthreads();
  }

  // ---- output embedding + zero pad: out[b,n,d<32] = cur@out_w[n] + out_b ----
  {
    const int d = t & 31, nq = t >> 5;
    for (int jj = 0; jj < 8; ++jj) {
      int n = nq + 8 * jj;
      const float* w = out_w + (size_t)n * H * FEAT + d;
      float a0 = 0, a1 = 0, a2 = 0, a3 = 0;
      for (int k4 = 0; k4 < 32; ++k4) {
        float4 c4 = *reinterpret_cast<const float4*>(&s_cur[n * PITCH + k4 * 4]);
        a0 += c4.x * w[(k4 * 4 + 0) * FEAT];
        a1 += c4.y * w[(k4 * 4 + 1) * FEAT];
        a2 += c4.z * w[(k4 * 4 + 2) * FEAT];
        a3 += c4.w * w[(k4 * 4 + 3) * FEAT];
      }
      ob[n * H + d] = (a0 + a1) + (a2 + a3) + out_b[n * FEAT + d];
    }
    #pragma unroll
    for (int q = 0; q < 6; ++q) {
      int idx4 = t + q * 256;                 // 1536 float4 spans of padding
      int n = idx4 / 24, c4i = idx4 - n * 24;
      *reinterpret_cast<float4*>(&ob[n * H + FEAT + c4i * 4]) =
          make_float4(0.f, 0.f, 0.f, 0.f);
    }
  }
}

extern "C" void kernel_launch(void* const* d_in, const int* in_sizes, int n_in,
                              void* d_out, int out_size, void* d_ws, size_t ws_size,
                              hipStream_t stream) {
  const float* x     = (const float*)d_in[0];
  const float* adj   = (const float*)d_in[1];
  const float* in_w  = (const float*)d_in[2];
  const float* in_b  = (const float*)d_in[3];
  const float* out_w = (const float*)d_in[4];
  const float* out_b = (const float*)d_in[5];
  const float* gc_w  = (const float*)d_in[6];
  const float* gc_b  = (const float*)d_in[7];
  const float* w_ih  = (const float*)d_in[8];
  const float* w_hh  = (const float*)d_in[9];
  const float* b_ih  = (const float*)d_in[10];
  const float* b_hh  = (const float*)d_in[11];
  (void)d_ws; (void)ws_size; (void)in_sizes; (void)n_in; (void)out_size;
  hipLaunchKernelGGL(mpnn_kernel, dim3(NB), dim3(256), 0, stream,
                     x, adj, in_w, in_b, out_w, out_b, gc_w, gc_b,
                     w_ih, w_hh, b_ih, b_hh, (float*)d_out);
}

// Round 2
// 1030.308 us; speedup vs baseline: 9.2498x; 9.2498x over previous
//
#include <hip/hip_runtime.h>
#include <cstdint>

#define NBATCH 4096
#define NNODE  64
#define FEAT   32
#define H      128
#define NE     4
#define NL     3

typedef __attribute__((ext_vector_type(8))) short short8;
typedef __attribute__((ext_vector_type(4))) short short4v;
typedef __attribute__((ext_vector_type(4))) float f32x4;
typedef __attribute__((ext_vector_type(2))) float f32x2;

__device__ __forceinline__ unsigned short f2b(float f) {
  union { float f; unsigned u; } v; v.f = f;
  unsigned u = v.u + 0x7FFFu + ((v.u >> 16) & 1u);   // RNE
  return (unsigned short)(u >> 16);
}
__device__ __forceinline__ float b2f(unsigned short s) {
  union { unsigned u; float f; } v; v.u = ((unsigned)s) << 16;
  return v.f;
}
__device__ __forceinline__ float sigm(float v) { return 1.0f / (1.0f + __expf(-v)); }
__device__ __forceinline__ float tanh_(float v) {
  v = fminf(fmaxf(v, -15.f), 15.f);
  float e = __expf(-2.f * v);
  return (1.f - e) / (1.f + e);
}
// swizzled tile indexing: 16B granules XORed with (row&7) to kill bank conflicts
__device__ __forceinline__ int gidx128(int r, int g) { return r * 128 + ((g ^ (r & 7)) << 3); }
__device__ __forceinline__ int idx128(int r, int k) { return gidx128(r, k >> 3) + (k & 7); }
__device__ __forceinline__ int gidx64(int r, int g) { return r * 64 + (((g ^ (r & 7)) & 7) << 3); }

__device__ __forceinline__ short8 pack8(const float* v) {
  short8 r;
  #pragma unroll
  for (int j = 0; j < 8; ++j) r[j] = (short)f2b(v[j]);
  return r;
}

// ================= K1: per-node input embedding -> bf16 h0 in out-row tails =============
__global__ __launch_bounds__(256, 2) void k_inemb(
    const float* __restrict__ x, const float* __restrict__ in_w,
    const float* __restrict__ in_b, float* __restrict__ out)
{
  __shared__ float s_wt[FEAT * H];   // [d][h]
  __shared__ float s_x[64 * FEAT];   // [r][d]
  const int t = threadIdx.x;
  const int n = blockIdx.x >> 6, bt = blockIdx.x & 63, b0 = bt * 64;
  const float* wsrc = in_w + (size_t)n * FEAT * H;
  #pragma unroll
  for (int it = 0; it < 4; ++it) {
    int i4 = t + it * 256;
    *(f32x4*)&s_wt[i4 * 4] = *(const f32x4*)&wsrc[i4 * 4];
  }
  {
    int r = t >> 2, q = t & 3;
    const float* xs = x + ((size_t)(b0 + r) * NNODE + n) * FEAT;
    *(f32x4*)&s_x[r * 32 + q * 8]     = *(const f32x4*)&xs[q * 8];
    *(f32x4*)&s_x[r * 32 + q * 8 + 4] = *(const f32x4*)&xs[q * 8 + 4];
  }
  __syncthreads();
  const int h2 = t & 63, rp = t >> 6;
  const float bi0 = in_b[n * H + 2 * h2], bi1 = in_b[n * H + 2 * h2 + 1];
  #pragma unroll 1
  for (int m = 0; m < 16; ++m) {
    int r = rp + 4 * m;
    float a0 = bi0, a1 = bi1;
    #pragma unroll
    for (int d = 0; d < 32; ++d) {
      float xv = s_x[r * 32 + d];
      f32x2 wv = *(const f32x2*)&s_wt[d * H + 2 * h2];
      a0 += xv * wv.x; a1 += xv * wv.y;
    }
    unsigned p = (unsigned)f2b(a0) | ((unsigned)f2b(a1) << 16);
    unsigned short* tail = (unsigned short*)(out + ((size_t)(b0 + r) * NNODE + n) * H + 64);
    *(unsigned*)(tail + 2 * h2) = p;
  }
}

// ================= K2: 3 layers of RGCN + GRU, all MFMA =============
__global__ __launch_bounds__(256, 2) void k_main(
    const float* __restrict__ adj,
    const float* __restrict__ gc_w, const float* __restrict__ gc_b,
    const float* __restrict__ w_ih, const float* __restrict__ w_hh,
    const float* __restrict__ b_ih, const float* __restrict__ b_hh,
    float* __restrict__ out)
{
  __shared__ unsigned short s_bufA[64 * 128];  // hidden buf A (swz rowmajor [i][h])
  __shared__ unsigned short s_bufB[64 * 128];  // hidden buf B
  __shared__ unsigned short s_u[128 * 64];     // union: S^T [h][j] / xf [i][h]
  __shared__ unsigned short s_w[128 * 64];     // union: W_e^T half [h][k] / GRU [48][128]
  __shared__ unsigned short s_adj[64 * 64];    // adj_e bf16 [i][j]
  __shared__ float s_bias[1280];               // gc_b layer slice | b_ih | b_hh

  const int t = threadIdx.x;
  const int b = blockIdx.x;
  const int w = t >> 6, lane = t & 63, lr = lane & 15, lq = lane >> 4;
  float* outb = out + (size_t)b * NNODE * H;

  unsigned short* cur = s_bufA;
  unsigned short* nxt = s_bufB;

  // phase 0: h0 (bf16) from out-row tails
  #pragma unroll
  for (int it = 0; it < 4; ++it) {
    int idx = t + it * 256;
    int n = idx >> 4, g = idx & 15;
    short8 v = *(const short8*)((const unsigned short*)(outb + n * H + 64) + g * 8);
    *(short8*)&cur[gidx128(n, g)] = v;
  }
  __syncthreads();

  #pragma unroll 1
  for (int layer = 0; layer < NL; ++layer) {
    // stage biases (visible after edge barriers)
    #pragma unroll
    for (int it = 0; it < 5; ++it) {
      int idx = t + it * 256;
      if (idx < 1280) {
        float v;
        if (idx < 512) v = gc_b[layer * 512 + idx];
        else if (idx < 896) v = b_ih[idx - 512];
        else v = b_hh[idx - 896];
        s_bias[idx] = v;
      }
    }

    f32x4 agg[8];
    #pragma unroll
    for (int tn = 0; tn < 8; ++tn) agg[tn] = f32x4{0.f, 0.f, 0.f, 0.f};

    #pragma unroll 1
    for (int e = 0; e < NE; ++e) {
      const float* adj_e = adj + (((size_t)b * NE + e) * NNODE * NNODE);
      const float* We = gc_w + (size_t)(layer * NE + e) * H * H;
      __syncthreads();  // prev edge's s_u/s_adj/s_w reads complete
      // stage adj_e -> bf16
      #pragma unroll
      for (int it = 0; it < 2; ++it) {
        int idx = t + it * 256;
        int i = idx >> 3, g = idx & 7;
        const float* src = adj_e + i * 64 + g * 8;
        float v[8];
        #pragma unroll
        for (int j = 0; j < 8; ++j) v[j] = src[j];
        *(short8*)&s_adj[gidx64(i, g)] = pack8(v);
      }
      f32x4 Sacc[8];
      #pragma unroll
      for (int tn = 0; tn < 8; ++tn) Sacc[tn] = f32x4{0.f, 0.f, 0.f, 0.f};

      #pragma unroll 1
      for (int kh = 0; kh < 2; ++kh) {
        if (kh) __syncthreads();  // kh=0 s_w reads done
        // stage W_e^T half: s_w[h][k-local], k = 64*kh + ...
        #pragma unroll
        for (int it = 0; it < 4; ++it) {
          int n = (t & 31) + 32 * it, g = t >> 5;
          float v[8];
          #pragma unroll
          for (int j = 0; j < 8; ++j) v[j] = We[(kh * 64 + g * 8 + j) * H + n];
          *(short8*)&s_w[gidx64(n, g)] = pack8(v);
        }
        __syncthreads();
        // mm1 partial: Sacc += cur @ W_e (k-half)
        #pragma unroll
        for (int ks = 0; ks < 2; ++ks) {
          short8 a = *(const short8*)&cur[gidx128(16 * w + lr, kh * 8 + ks * 4 + lq)];
          #pragma unroll
          for (int tn = 0; tn < 8; ++tn) {
            short8 bb = *(const short8*)&s_w[gidx64(16 * tn + lr, ks * 4 + lq)];
            Sacc[tn] = __builtin_amdgcn_mfma_f32_16x16x32_bf16(a, bb, Sacc[tn], 0, 0, 0);
          }
        }
      }
      // write S^T (bf16) into s_u: lane holds S[n=16w+4lq+r][h=16tn+lr]
      {
        int nb = 16 * w + 4 * lq;
        int g = nb >> 3, sub = nb & 7;
        #pragma unroll
        for (int tn = 0; tn < 8; ++tn) {
          int h = 16 * tn + lr;
          short4v p;
          #pragma unroll
          for (int r = 0; r < 4; ++r) p[r] = (short)f2b(Sacc[tn][r]);
          *(short4v*)&s_u[gidx64(h, g) + sub] = p;
        }
      }
      __syncthreads();
      // mm2: O = adj_e @ S ; agg += relu(O + bias)/4
      {
        f32x4 Oacc[8];
        #pragma unroll
        for (int tn = 0; tn < 8; ++tn) Oacc[tn] = f32x4{0.f, 0.f, 0.f, 0.f};
        #pragma unroll
        for (int ks = 0; ks < 2; ++ks) {
          short8 a = *(const short8*)&s_adj[gidx64(16 * w + lr, ks * 4 + lq)];
          #pragma unroll
          for (int tn = 0; tn < 8; ++tn) {
            short8 bb = *(const short8*)&s_u[gidx64(16 * tn + lr, ks * 4 + lq)];
            Oacc[tn] = __builtin_amdgcn_mfma_f32_16x16x32_bf16(a, bb, Oacc[tn], 0, 0, 0);
          }
        }
        #pragma unroll
        for (int tn = 0; tn < 8; ++tn) {
          float bias = s_bias[e * 128 + 16 * tn + lr];
          #pragma unroll
          for (int r = 0; r < 4; ++r)
            agg[tn][r] += 0.25f * fmaxf(Oacc[tn][r] + bias, 0.f);
        }
      }
    }  // edges
    __syncthreads();  // s_u (S^T) reads done
    // xf = agg -> s_u row-major [i][h]
    #pragma unroll
    for (int tn = 0; tn < 8; ++tn) {
      int h = 16 * tn + lr;
      #pragma unroll
      for (int r = 0; r < 4; ++r) {
        int i = 16 * w + 4 * lq + r;
        s_u[idx128(i, h)] = f2b(agg[tn][r]);
      }
    }
    __syncthreads();

    // GRU over 8 mH-chunks of 16
    #pragma unroll 1
    for (int c = 0; c < 8; ++c) {
      // stage w_ih chunk rows {g*128 + 16c + 0..15}
      #pragma unroll
      for (int it = 0; it < 3; ++it) {
        int idx = t + it * 256;
        int rr = idx >> 4, g = idx & 15;
        int mrow = (rr >> 4) * 128 + 16 * c + (rr & 15);
        const float* src = w_ih + mrow * H + g * 8;
        float v[8];
        #pragma unroll
        for (int j = 0; j < 8; ++j) v[j] = src[j];
        *(short8*)&s_w[gidx128(rr, g)] = pack8(v);
      }
      __syncthreads();
      f32x4 gi[3], gh[3];
      #pragma unroll
      for (int tg = 0; tg < 3; ++tg) gi[tg] = f32x4{0.f, 0.f, 0.f, 0.f};
      #pragma unroll
      for (int ks = 0; ks < 4; ++ks) {
        short8 bb = *(const short8*)&s_u[gidx128(16 * w + lr, ks * 4 + lq)];
        #pragma unroll
        for (int tg = 0; tg < 3; ++tg) {
          short8 a = *(const short8*)&s_w[gidx128(16 * tg + lr, ks * 4 + lq)];
          gi[tg] = __builtin_amdgcn_mfma_f32_16x16x32_bf16(a, bb, gi[tg], 0, 0, 0);
        }
      }
      __syncthreads();
      // stage w_hh chunk
      #pragma unroll
      for (int it = 0; it < 3; ++it) {
        int idx = t + it * 256;
        int rr = idx >> 4, g = idx & 15;
        int mrow = (rr >> 4) * 128 + 16 * c + (rr & 15);
        const float* src = w_hh + mrow * H + g * 8;
        float v[8];
        #pragma unroll
        for (int j = 0; j < 8; ++j) v[j] = src[j];
        *(short8*)&s_w[gidx128(rr, g)] = pack8(v);
      }
      __syncthreads();
      #pragma unroll
      for (int tg = 0; tg < 3; ++tg) gh[tg] = f32x4{0.f, 0.f, 0.f, 0.f};
      #pragma unroll
      for (int ks = 0; ks < 4; ++ks) {
        short8 bb = *(const short8*)&cur[gidx128(16 * w + lr, ks * 4 + lq)];
        #pragma unroll
        for (int tg = 0; tg < 3; ++tg) {
          short8 a = *(const short8*)&s_w[gidx128(16 * tg + lr, ks * 4 + lq)];
          gh[tg] = __builtin_amdgcn_mfma_f32_16x16x32_bf16(a, bb, gh[tg], 0, 0, 0);
        }
      }
      // gates (lane-local): lane -> i = 16w+lr, mH = 16c + 4lq + r
      {
        int i = 16 * w + lr;
        int g = (16 * c + 4 * lq) >> 3;
        int off = gidx128(i, g) + ((4 * lq) & 7);
        short4v hv = *(const short4v*)&cur[off];
        short4v hp;
        #pragma unroll
        for (int r = 0; r < 4; ++r) {
          int mH = 16 * c + 4 * lq + r;
          float rg = sigm(gi[0][r] + s_bias[512 + mH] + gh[0][r] + s_bias[896 + mH]);
          float zg = sigm(gi[1][r] + s_bias[640 + mH] + gh[1][r] + s_bias[1024 + mH]);
          float ng = tanh_(gi[2][r] + s_bias[768 + mH] + rg * (gh[2][r] + s_bias[1152 + mH]));
          float hold = b2f((unsigned short)hv[r]);
          hp[r] = (short)f2b((1.f - zg) * ng + zg * hold);
        }
        *(short4v*)&nxt[off] = hp;
      }
      __syncthreads();
    }  // chunks
    { unsigned short* tmp = cur; cur = nxt; nxt = tmp; }
  }  // layers

  // write final hidden (bf16) back into out-row tails
  #pragma unroll
  for (int it = 0; it < 4; ++it) {
    int idx = t + it * 256;
    int n = idx >> 4, g = idx & 15;
    short8 v = *(const short8*)&cur[gidx128(n, g)];
    *(short8*)((unsigned short*)(outb + n * H + 64) + g * 8) = v;
  }
}

// ================= K3: per-node output embedding + zero pad =============
__global__ __launch_bounds__(256, 2) void k_outemb(
    const float* __restrict__ out_w, const float* __restrict__ out_b,
    float* __restrict__ out)
{
  __shared__ float s_wt[H * FEAT];   // [k][d]
  __shared__ float s_c[64 * 132];    // cur f32, padded pitch
  const int t = threadIdx.x;
  const int n = blockIdx.x >> 6, bt = blockIdx.x & 63, b0 = bt * 64;
  const float* wsrc = out_w + (size_t)n * H * FEAT;
  #pragma unroll
  for (int it = 0; it < 4; ++it) {
    int i4 = t + it * 256;
    *(f32x4*)&s_wt[i4 * 4] = *(const f32x4*)&wsrc[i4 * 4];
  }
  #pragma unroll
  for (int it = 0; it < 4; ++it) {
    int idx = t + it * 256;
    int r = idx >> 4, g = idx & 15;
    const unsigned short* tail =
        (const unsigned short*)(out + ((size_t)(b0 + r) * NNODE + n) * H + 64);
    short8 v = *(const short8*)(tail + g * 8);
    #pragma unroll
    for (int j = 0; j < 8; ++j) s_c[r * 132 + g * 8 + j] = b2f((unsigned short)v[j]);
  }
  __syncthreads();  // all tail reads done; LDS visible
  const int d = t & 31, rq = t >> 5;
  const float bias = out_b[n * FEAT + d];
  float accs[8];
  #pragma unroll
  for (int m = 0; m < 8; ++m) {
    int r = rq + 8 * m;
    float a = bias;
    #pragma unroll 8
    for (int k = 0; k < H; ++k) a += s_c[r * 132 + k] * s_wt[k * FEAT + d];
    accs[m] = a;
  }
  #pragma unroll
  for (int m = 0; m < 8; ++m) {
    int r = rq + 8 * m;
    out[((size_t)(b0 + r) * NNODE + n) * H + d] = accs[m];
  }
  #pragma unroll
  for (int q = 0; q < 6; ++q) {
    int idx = t + q * 256;           // 1536 float4 spans: 64 rows x 24
    int r = idx / 24, c4 = idx - r * 24;
    *(f32x4*)&out[((size_t)(b0 + r) * NNODE + n) * H + FEAT + c4 * 4] =
        f32x4{0.f, 0.f, 0.f, 0.f};
  }
}

extern "C" void kernel_launch(void* const* d_in, const int* in_sizes, int n_in,
                              void* d_out, int out_size, void* d_ws, size_t ws_size,
                              hipStream_t stream) {
  const float* x     = (const float*)d_in[0];
  const float* adj   = (const float*)d_in[1];
  const float* in_w  = (const float*)d_in[2];
  const float* in_b  = (const float*)d_in[3];
  const float* out_w = (const float*)d_in[4];
  const float* out_b = (const float*)d_in[5];
  const float* gc_w  = (const float*)d_in[6];
  const float* gc_b  = (const float*)d_in[7];
  const float* w_ih  = (const float*)d_in[8];
  const float* w_hh  = (const float*)d_in[9];
  const float* b_ih  = (const float*)d_in[10];
  const float* b_hh  = (const float*)d_in[11];
  (void)d_ws; (void)ws_size; (void)in_sizes; (void)n_in; (void)out_size;
  hipLaunchKernelGGL(k_inemb, dim3(NBATCH), dim3(256), 0, stream, x, in_w, in_b, (float*)d_out);
  hipLaunchKernelGGL(k_main, dim3(NBATCH), dim3(256), 0, stream,
                     adj, gc_w, gc_b, w_ih, w_hh, b_ih, b_hh, (float*)d_out);
  hipLaunchKernelGGL(k_outemb, dim3(NBATCH), dim3(256), 0, stream, out_w, out_b, (float*)d_out);
}

// Round 3
// 851.157 us; speedup vs baseline: 11.1967x; 1.2105x over previous
//
#include <hip/hip_runtime.h>
#include <cstdint>

#define NBATCH 4096
#define NNODE  64
#define FEAT   32
#define H      128
#define NE     4
#define NL     3

typedef __attribute__((ext_vector_type(8))) short short8;
typedef __attribute__((ext_vector_type(4))) short short4v;
typedef __attribute__((ext_vector_type(4))) float f32x4;
typedef __attribute__((ext_vector_type(2))) float f32x2;

// ws image sizes (bytes)
#define IMG_GC_ELEMS   (128 * 64)          // one (layer,edge,kh) image, shorts
#define IMG_GRU_ELEMS  (48 * 128)          // one (mat,chunk) image, shorts
#define IMG_GC_BYTES   (24 * IMG_GC_ELEMS * 2)    // 393216
#define IMG_GRU_BYTES  (16 * IMG_GRU_ELEMS * 2)   // 196608
#define WS_NEEDED      (IMG_GC_BYTES + IMG_GRU_BYTES)

__device__ __forceinline__ unsigned short f2b(float f) {
  union { float f; unsigned u; } v; v.f = f;
  unsigned u = v.u + 0x7FFFu + ((v.u >> 16) & 1u);   // RNE
  return (unsigned short)(u >> 16);
}
__device__ __forceinline__ float b2f(unsigned short s) {
  union { unsigned u; float f; } v; v.u = ((unsigned)s) << 16;
  return v.f;
}
__device__ __forceinline__ float sigm(float v) { return 1.0f / (1.0f + __expf(-v)); }
__device__ __forceinline__ float tanh_(float v) {
  v = fminf(fmaxf(v, -15.f), 15.f);
  float e = __expf(-2.f * v);
  return (1.f - e) / (1.f + e);
}
// swizzled tile indexing: 16B granules XORed with (row&7) to kill bank conflicts
__device__ __forceinline__ int gidx128(int r, int g) { return r * 128 + ((g ^ (r & 7)) << 3); }
__device__ __forceinline__ int idx128(int r, int k) { return gidx128(r, k >> 3) + (k & 7); }
__device__ __forceinline__ int gidx64(int r, int g) { return r * 64 + (((g ^ (r & 7)) & 7) << 3); }

__device__ __forceinline__ short8 pack8(const float* v) {
  short8 r;
  #pragma unroll
  for (int j = 0; j < 8; ++j) r[j] = (short)f2b(v[j]);
  return r;
}

// async global->LDS, 16B per lane; LDS dest wave-uniform base + lane*16
__device__ __forceinline__ void gll16(const void* g, void* l) {
  __builtin_amdgcn_global_load_lds(
      (const __attribute__((address_space(1))) unsigned int*)g,
      (__attribute__((address_space(3))) unsigned int*)l, 16, 0, 0);
}

// ============ K0: build bf16 weight images in ws (exact swizzled LDS byte order) ========
// grid 40: blk<24 -> gc (l*8+e*2+kh); blk>=24 -> gru ((blk-24): m*8+c)
__global__ __launch_bounds__(256, 2) void k_prep(
    const float* __restrict__ gc_w, const float* __restrict__ w_ih,
    const float* __restrict__ w_hh, unsigned short* __restrict__ ws)
{
  const int t = threadIdx.x;
  if (blockIdx.x < 24) {
    const int blk = blockIdx.x;
    const int kh = blk & 1, e = (blk >> 1) & 3, l = blk >> 3;
    const float* We = gc_w + (size_t)(l * NE + e) * H * H;
    unsigned short* dst = ws + (size_t)blk * IMG_GC_ELEMS;
    #pragma unroll
    for (int it = 0; it < 4; ++it) {
      int idx = t + it * 256;            // 0..1023
      int r = idx >> 3, g = idx & 7;     // r: out col 0..127, g: k granule
      float v[8];
      #pragma unroll
      for (int j = 0; j < 8; ++j) v[j] = We[(kh * 64 + g * 8 + j) * H + r];
      *(short8*)&dst[gidx64(r, g)] = pack8(v);
    }
  } else {
    const int blk = blockIdx.x - 24;
    const int c = blk & 7, m = blk >> 3;
    const float* Mat = m ? w_hh : w_ih;
    unsigned short* dst = ws + IMG_GC_BYTES / 2 + (size_t)blk * IMG_GRU_ELEMS;
    #pragma unroll
    for (int it = 0; it < 3; ++it) {
      int idx = t + it * 256;            // 0..767
      int rr = idx >> 4, g = idx & 15;   // rr: 0..47 (3 gates x 16 rows)
      int mrow = (rr >> 4) * H + 16 * c + (rr & 15);
      float v[8];
      #pragma unroll
      for (int j = 0; j < 8; ++j) v[j] = Mat[mrow * H + g * 8 + j];
      *(short8*)&dst[gidx128(rr, g)] = pack8(v);
    }
  }
}

// ================= K1: per-node input embedding -> bf16 h0 in out-row tails =============
__global__ __launch_bounds__(256, 2) void k_inemb(
    const float* __restrict__ x, const float* __restrict__ in_w,
    const float* __restrict__ in_b, float* __restrict__ out)
{
  __shared__ float s_wt[FEAT * H];   // [d][h]
  __shared__ float s_x[64 * FEAT];   // [r][d]
  const int t = threadIdx.x;
  const int n = blockIdx.x >> 6, bt = blockIdx.x & 63, b0 = bt * 64;
  const float* wsrc = in_w + (size_t)n * FEAT * H;
  #pragma unroll
  for (int it = 0; it < 4; ++it) {
    int i4 = t + it * 256;
    *(f32x4*)&s_wt[i4 * 4] = *(const f32x4*)&wsrc[i4 * 4];
  }
  {
    int r = t >> 2, q = t & 3;
    const float* xs = x + ((size_t)(b0 + r) * NNODE + n) * FEAT;
    *(f32x4*)&s_x[r * 32 + q * 8]     = *(const f32x4*)&xs[q * 8];
    *(f32x4*)&s_x[r * 32 + q * 8 + 4] = *(const f32x4*)&xs[q * 8 + 4];
  }
  __syncthreads();
  const int h2 = t & 63, rp = t >> 6;
  const float bi0 = in_b[n * H + 2 * h2], bi1 = in_b[n * H + 2 * h2 + 1];
  #pragma unroll 1
  for (int m = 0; m < 16; ++m) {
    int r = rp + 4 * m;
    float a0 = bi0, a1 = bi1;
    #pragma unroll
    for (int d = 0; d < 32; ++d) {
      float xv = s_x[r * 32 + d];
      f32x2 wv = *(const f32x2*)&s_wt[d * H + 2 * h2];
      a0 += xv * wv.x; a1 += xv * wv.y;
    }
    unsigned p = (unsigned)f2b(a0) | ((unsigned)f2b(a1) << 16);
    unsigned short* tail = (unsigned short*)(out + ((size_t)(b0 + r) * NNODE + n) * H + 64);
    *(unsigned*)(tail + 2 * h2) = p;
  }
}

// ================= K2: 3 layers of RGCN + GRU, all MFMA =============
template <bool PRE>
__global__ __launch_bounds__(256, 2) void k_main(
    const float* __restrict__ adj,
    const float* __restrict__ gc_w, const float* __restrict__ gc_b,
    const float* __restrict__ w_ih, const float* __restrict__ w_hh,
    const float* __restrict__ b_ih, const float* __restrict__ b_hh,
    const unsigned short* __restrict__ wimg,
    float* __restrict__ out)
{
  __shared__ unsigned short s_bufA[64 * 128];  // hidden buf A (swz rowmajor [i][h])
  __shared__ unsigned short s_bufB[64 * 128];  // hidden buf B
  __shared__ unsigned short s_u[128 * 64];     // union: S^T [h][j] / xf [i][h]
  __shared__ unsigned short s_w[128 * 64];     // union: W_e^T half / GRU chunk [48][128]
  __shared__ unsigned short s_adj[64 * 64];    // adj_e bf16 [i][j]
  __shared__ float s_bias[1280];               // gc_b layer slice | b_ih | b_hh

  const int t = threadIdx.x;
  const int b = blockIdx.x;
  const int w = t >> 6, lane = t & 63, lr = lane & 15, lq = lane >> 4;
  float* outb = out + (size_t)b * NNODE * H;

  const unsigned short* img_gru = wimg + IMG_GC_BYTES / 2;

  unsigned short* cur = s_bufA;
  unsigned short* nxt = s_bufB;

  // phase 0: h0 (bf16) from out-row tails
  #pragma unroll
  for (int it = 0; it < 4; ++it) {
    int idx = t + it * 256;
    int n = idx >> 4, g = idx & 15;
    short8 v = *(const short8*)((const unsigned short*)(outb + n * H + 64) + g * 8);
    *(short8*)&cur[gidx128(n, g)] = v;
  }
  __syncthreads();

  #pragma unroll 1
  for (int layer = 0; layer < NL; ++layer) {
    // stage biases (visible after edge barriers)
    #pragma unroll
    for (int it = 0; it < 5; ++it) {
      int idx = t + it * 256;
      if (idx < 1280) {
        float v;
        if (idx < 512) v = gc_b[layer * 512 + idx];
        else if (idx < 896) v = b_ih[idx - 512];
        else v = b_hh[idx - 896];
        s_bias[idx] = v;
      }
    }

    f32x4 agg[8];
    #pragma unroll
    for (int tn = 0; tn < 8; ++tn) agg[tn] = f32x4{0.f, 0.f, 0.f, 0.f};

    #pragma unroll 1
    for (int e = 0; e < NE; ++e) {
      const float* adj_e = adj + (((size_t)b * NE + e) * NNODE * NNODE);
      const float* We = gc_w + (size_t)(layer * NE + e) * H * H;
      const unsigned short* img_e = wimg + (size_t)((layer * NE + e) * 2) * IMG_GC_ELEMS;
      __syncthreads();  // prev edge's s_u/s_adj/s_w reads complete
      if (PRE) {        // issue W_e^T (kh=0) async stage
        #pragma unroll
        for (int it = 0; it < 4; ++it) {
          int off = (it * 4 + w) * 1024;
          gll16((const char*)img_e + off + lane * 16, (char*)s_w + off);
        }
      }
      // stage adj_e -> bf16
      #pragma unroll
      for (int it = 0; it < 2; ++it) {
        int idx = t + it * 256;
        int i = idx >> 3, g = idx & 7;
        const float* src = adj_e + i * 64 + g * 8;
        float v[8];
        #pragma unroll
        for (int j = 0; j < 8; ++j) v[j] = src[j];
        *(short8*)&s_adj[gidx64(i, g)] = pack8(v);
      }
      f32x4 Sacc[8];
      #pragma unroll
      for (int tn = 0; tn < 8; ++tn) Sacc[tn] = f32x4{0.f, 0.f, 0.f, 0.f};

      #pragma unroll 1
      for (int kh = 0; kh < 2; ++kh) {
        if (kh) {
          __syncthreads();  // kh=0 s_w reads done
          if (PRE) {
            #pragma unroll
            for (int it = 0; it < 4; ++it) {
              int off = (it * 4 + w) * 1024;
              gll16((const char*)(img_e + IMG_GC_ELEMS) + off + lane * 16, (char*)s_w + off);
            }
          }
        }
        if (!PRE) {
          // legacy gather-stage W_e^T half: s_w[h][k-local]
          #pragma unroll
          for (int it = 0; it < 4; ++it) {
            int n = (t & 31) + 32 * it, g = t >> 5;
            float v[8];
            #pragma unroll
            for (int j = 0; j < 8; ++j) v[j] = We[(kh * 64 + g * 8 + j) * H + n];
            *(short8*)&s_w[gidx64(n, g)] = pack8(v);
          }
        }
        __syncthreads();
        // mm1 partial: Sacc += cur @ W_e (k-half)
        #pragma unroll
        for (int ks = 0; ks < 2; ++ks) {
          short8 a = *(const short8*)&cur[gidx128(16 * w + lr, kh * 8 + ks * 4 + lq)];
          #pragma unroll
          for (int tn = 0; tn < 8; ++tn) {
            short8 bb = *(const short8*)&s_w[gidx64(16 * tn + lr, ks * 4 + lq)];
            Sacc[tn] = __builtin_amdgcn_mfma_f32_16x16x32_bf16(a, bb, Sacc[tn], 0, 0, 0);
          }
        }
      }
      // write S^T (bf16) into s_u: lane holds S[n=16w+4lq+r][h=16tn+lr]
      {
        int nb = 16 * w + 4 * lq;
        int g = nb >> 3, sub = nb & 7;
        #pragma unroll
        for (int tn = 0; tn < 8; ++tn) {
          int h = 16 * tn + lr;
          short4v p;
          #pragma unroll
          for (int r = 0; r < 4; ++r) p[r] = (short)f2b(Sacc[tn][r]);
          *(short4v*)&s_u[gidx64(h, g) + sub] = p;
        }
      }
      __syncthreads();
      // mm2: O = adj_e @ S ; agg += relu(O + bias)/4
      {
        f32x4 Oacc[8];
        #pragma unroll
        for (int tn = 0; tn < 8; ++tn) Oacc[tn] = f32x4{0.f, 0.f, 0.f, 0.f};
        #pragma unroll
        for (int ks = 0; ks < 2; ++ks) {
          short8 a = *(const short8*)&s_adj[gidx64(16 * w + lr, ks * 4 + lq)];
          #pragma unroll
          for (int tn = 0; tn < 8; ++tn) {
            short8 bb = *(const short8*)&s_u[gidx64(16 * tn + lr, ks * 4 + lq)];
            Oacc[tn] = __builtin_amdgcn_mfma_f32_16x16x32_bf16(a, bb, Oacc[tn], 0, 0, 0);
          }
        }
        #pragma unroll
        for (int tn = 0; tn < 8; ++tn) {
          float bias = s_bias[e * 128 + 16 * tn + lr];
          #pragma unroll
          for (int r = 0; r < 4; ++r)
            agg[tn][r] += 0.25f * fmaxf(Oacc[tn][r] + bias, 0.f);
        }
      }
    }  // edges
    __syncthreads();  // s_u (S^T) reads done
    // xf = agg -> s_u row-major [i][h]
    #pragma unroll
    for (int tn = 0; tn < 8; ++tn) {
      int h = 16 * tn + lr;
      #pragma unroll
      for (int r = 0; r < 4; ++r) {
        int i = 16 * w + 4 * lq + r;
        s_u[idx128(i, h)] = f2b(agg[tn][r]);
      }
    }
    __syncthreads();

    // GRU over 8 mH-chunks of 16
    #pragma unroll 1
    for (int c = 0; c < 8; ++c) {
      // stage w_ih chunk rows {g*128 + 16c + 0..15}
      if (PRE) {
        const unsigned short* img_c = img_gru + (size_t)c * IMG_GRU_ELEMS;
        #pragma unroll
        for (int it = 0; it < 3; ++it) {
          int off = (it * 4 + w) * 1024;
          gll16((const char*)img_c + off + lane * 16, (char*)s_w + off);
        }
      } else {
        #pragma unroll
        for (int it = 0; it < 3; ++it) {
          int idx = t + it * 256;
          int rr = idx >> 4, g = idx & 15;
          int mrow = (rr >> 4) * H + 16 * c + (rr & 15);
          const float* src = w_ih + mrow * H + g * 8;
          float v[8];
          #pragma unroll
          for (int j = 0; j < 8; ++j) v[j] = src[j];
          *(short8*)&s_w[gidx128(rr, g)] = pack8(v);
        }
      }
      __syncthreads();
      f32x4 gi[3], gh[3];
      #pragma unroll
      for (int tg = 0; tg < 3; ++tg) gi[tg] = f32x4{0.f, 0.f, 0.f, 0.f};
      #pragma unroll
      for (int ks = 0; ks < 4; ++ks) {
        short8 bb = *(const short8*)&s_u[gidx128(16 * w + lr, ks * 4 + lq)];
        #pragma unroll
        for (int tg = 0; tg < 3; ++tg) {
          short8 a = *(const short8*)&s_w[gidx128(16 * tg + lr, ks * 4 + lq)];
          gi[tg] = __builtin_amdgcn_mfma_f32_16x16x32_bf16(a, bb, gi[tg], 0, 0, 0);
        }
      }
      __syncthreads();
      // stage w_hh chunk
      if (PRE) {
        const unsigned short* img_c = img_gru + (size_t)(8 + c) * IMG_GRU_ELEMS;
        #pragma unroll
        for (int it = 0; it < 3; ++it) {
          int off = (it * 4 + w) * 1024;
          gll16((const char*)img_c + off + lane * 16, (char*)s_w + off);
        }
      } else {
        #pragma unroll
        for (int it = 0; it < 3; ++it) {
          int idx = t + it * 256;
          int rr = idx >> 4, g = idx & 15;
          int mrow = (rr >> 4) * H + 16 * c + (rr & 15);
          const float* src = w_hh + mrow * H + g * 8;
          float v[8];
          #pragma unroll
          for (int j = 0; j < 8; ++j) v[j] = src[j];
          *(short8*)&s_w[gidx128(rr, g)] = pack8(v);
        }
      }
      __syncthreads();
      #pragma unroll
      for (int tg = 0; tg < 3; ++tg) gh[tg] = f32x4{0.f, 0.f, 0.f, 0.f};
      #pragma unroll
      for (int ks = 0; ks < 4; ++ks) {
        short8 bb = *(const short8*)&cur[gidx128(16 * w + lr, ks * 4 + lq)];
        #pragma unroll
        for (int tg = 0; tg < 3; ++tg) {
          short8 a = *(const short8*)&s_w[gidx128(16 * tg + lr, ks * 4 + lq)];
          gh[tg] = __builtin_amdgcn_mfma_f32_16x16x32_bf16(a, bb, gh[tg], 0, 0, 0);
        }
      }
      // gates (lane-local): lane -> i = 16w+lr, mH = 16c + 4lq + r
      {
        int i = 16 * w + lr;
        int g = (16 * c + 4 * lq) >> 3;
        int off = gidx128(i, g) + ((4 * lq) & 7);
        short4v hv = *(const short4v*)&cur[off];
        short4v hp;
        #pragma unroll
        for (int r = 0; r < 4; ++r) {
          int mH = 16 * c + 4 * lq + r;
          float rg = sigm(gi[0][r] + s_bias[512 + mH] + gh[0][r] + s_bias[896 + mH]);
          float zg = sigm(gi[1][r] + s_bias[640 + mH] + gh[1][r] + s_bias[1024 + mH]);
          float ng = tanh_(gi[2][r] + s_bias[768 + mH] + rg * (gh[2][r] + s_bias[1152 + mH]));
          float hold = b2f((unsigned short)hv[r]);
          hp[r] = (short)f2b((1.f - zg) * ng + zg * hold);
        }
        *(short4v*)&nxt[off] = hp;
      }
      __syncthreads();
    }  // chunks
    { unsigned short* tmp = cur; cur = nxt; nxt = tmp; }
  }  // layers

  // write final hidden (bf16) back into out-row tails
  #pragma unroll
  for (int it = 0; it < 4; ++it) {
    int idx = t + it * 256;
    int n = idx >> 4, g = idx & 15;
    short8 v = *(const short8*)&cur[gidx128(n, g)];
    *(short8*)((unsigned short*)(outb + n * H + 64) + g * 8) = v;
  }
}

// ================= K3: per-node output embedding + zero pad =============
__global__ __launch_bounds__(256, 2) void k_outemb(
    const float* __restrict__ out_w, const float* __restrict__ out_b,
    float* __restrict__ out)
{
  __shared__ float s_wt[H * FEAT];   // [k][d]
  __shared__ float s_c[64 * 132];    // cur f32, padded pitch
  const int t = threadIdx.x;
  const int n = blockIdx.x >> 6, bt = blockIdx.x & 63, b0 = bt * 64;
  const float* wsrc = out_w + (size_t)n * H * FEAT;
  #pragma unroll
  for (int it = 0; it < 4; ++it) {
    int i4 = t + it * 256;
    *(f32x4*)&s_wt[i4 * 4] = *(const f32x4*)&wsrc[i4 * 4];
  }
  #pragma unroll
  for (int it = 0; it < 4; ++it) {
    int idx = t + it * 256;
    int r = idx >> 4, g = idx & 15;
    const unsigned short* tail =
        (const unsigned short*)(out + ((size_t)(b0 + r) * NNODE + n) * H + 64);
    short8 v = *(const short8*)(tail + g * 8);
    #pragma unroll
    for (int j = 0; j < 8; ++j) s_c[r * 132 + g * 8 + j] = b2f((unsigned short)v[j]);
  }
  __syncthreads();  // all tail reads done; LDS visible
  const int d = t & 31, rq = t >> 5;
  const float bias = out_b[n * FEAT + d];
  float accs[8];
  #pragma unroll
  for (int m = 0; m < 8; ++m) {
    int r = rq + 8 * m;
    float a = bias;
    #pragma unroll 8
    for (int k = 0; k < H; ++k) a += s_c[r * 132 + k] * s_wt[k * FEAT + d];
    accs[m] = a;
  }
  #pragma unroll
  for (int m = 0; m < 8; ++m) {
    int r = rq + 8 * m;
    out[((size_t)(b0 + r) * NNODE + n) * H + d] = accs[m];
  }
  #pragma unroll
  for (int q = 0; q < 6; ++q) {
    int idx = t + q * 256;           // 1536 float4 spans: 64 rows x 24
    int r = idx / 24, c4 = idx - r * 24;
    *(f32x4*)&out[((size_t)(b0 + r) * NNODE + n) * H + FEAT + c4 * 4] =
        f32x4{0.f, 0.f, 0.f, 0.f};
  }
}

extern "C" void kernel_launch(void* const* d_in, const int* in_sizes, int n_in,
                              void* d_out, int out_size, void* d_ws, size_t ws_size,
                              hipStream_t stream) {
  const float* x     = (const float*)d_in[0];
  const float* adj   = (const float*)d_in[1];
  const float* in_w  = (const float*)d_in[2];
  const float* in_b  = (const float*)d_in[3];
  const float* out_w = (const float*)d_in[4];
  const float* out_b = (const float*)d_in[5];
  const float* gc_w  = (const float*)d_in[6];
  const float* gc_b  = (const float*)d_in[7];
  const float* w_ih  = (const float*)d_in[8];
  const float* w_hh  = (const float*)d_in[9];
  const float* b_ih  = (const float*)d_in[10];
  const float* b_hh  = (const float*)d_in[11];
  (void)in_sizes; (void)n_in; (void)out_size;
  hipLaunchKernelGGL(k_inemb, dim3(NBATCH), dim3(256), 0, stream, x, in_w, in_b, (float*)d_out);
  if (ws_size >= (size_t)WS_NEEDED) {
    unsigned short* wimg = (unsigned short*)d_ws;
    hipLaunchKernelGGL(k_prep, dim3(40), dim3(256), 0, stream, gc_w, w_ih, w_hh, wimg);
    hipLaunchKernelGGL(k_main<true>, dim3(NBATCH), dim3(256), 0, stream,
                       adj, gc_w, gc_b, w_ih, w_hh, b_ih, b_hh, wimg, (float*)d_out);
  } else {
    hipLaunchKernelGGL(k_main<false>, dim3(NBATCH), dim3(256), 0, stream,
                       adj, gc_w, gc_b, w_ih, w_hh, b_ih, b_hh,
                       (const unsigned short*)nullptr, (float*)d_out);
  }
  hipLaunchKernelGGL(k_outemb, dim3(NBATCH), dim3(256), 0, stream, out_w, out_b, (float*)d_out);
}